// Round 18
// baseline (1512.493 us; speedup 1.0000x reference)
//
#include <hip/hip_runtime.h>

typedef float f32x4 __attribute__((ext_vector_type(4)));
typedef __bf16 bf16x8 __attribute__((ext_vector_type(8)));

#define NROWS 16384   // B*S
#define SEQ   4096
#define EMBD  512
#define MLPD  2048

__device__ inline float gelu_tanh(float x) {
    float t = 0.7978845608028654f * (x + 0.044715f * x * x * x);
    float e = __expf(2.f * t);
    float th = 1.f - 2.f / (1.f + e);
    return 0.5f * x * (1.f + th);
}

// direct global->LDS 16B DMA; LDS dest must be linear in lane order
#define GLOAD16(gp, lp)                                                        \
    __builtin_amdgcn_global_load_lds(                                          \
        (const __attribute__((address_space(1))) void*)(gp),                   \
        (__attribute__((address_space(3))) void*)(lp), 16, 0, 0)

// ---------------- positional table: pos[s][512] ----------------
__global__ void pos_kernel(float* __restrict__ pos) {
    int i = blockIdx.x * 256 + threadIdx.x;        // 4096*256
    int s = i >> 8, j = i & 255;
    float div = __expf((float)j * (-2.f * 9.210340371976184f / 512.f));
    float a = (float)s * div;
    pos[(size_t)s * 512 + 2 * j]     = sinf(a);
    pos[(size_t)s * 512 + 2 * j + 1] = cosf(a);
}

// ---------------- embedding gather + pos add + LN(layer0) ----------------
__global__ __launch_bounds__(256) void embed_ln(
    const int* __restrict__ tokens, const float* __restrict__ embed,
    const float* __restrict__ pos, const float* __restrict__ gamma,
    const float* __restrict__ beta, float* __restrict__ x,
    __bf16* __restrict__ h) {
    int lane = threadIdx.x & 63;
    size_t row = (size_t)blockIdx.x * 4 + (threadIdx.x >> 6);
    int s = (int)(row & (SEQ - 1));
    int tok = tokens[row];
    const float* ep = embed + (size_t)tok * 512 + lane * 8;
    const float* pp = pos + (size_t)s * 512 + lane * 8;
    f32x4 v0 = *(const f32x4*)ep + *(const f32x4*)pp;
    f32x4 v1 = *(const f32x4*)(ep + 4) + *(const f32x4*)(pp + 4);
    *(f32x4*)(x + row * 512 + lane * 8) = v0;
    *(f32x4*)(x + row * 512 + lane * 8 + 4) = v1;
    float sum = (v0[0] + v0[1]) + (v0[2] + v0[3]) + (v1[0] + v1[1]) + (v1[2] + v1[3]);
    #pragma unroll
    for (int off = 32; off; off >>= 1) sum += __shfl_xor(sum, off);
    float mu = sum * (1.f / 512.f);
    float vs = 0.f;
    #pragma unroll
    for (int j = 0; j < 4; j++) {
        float d0 = v0[j] - mu; vs += d0 * d0;
        float d1 = v1[j] - mu; vs += d1 * d1;
    }
    #pragma unroll
    for (int off = 32; off; off >>= 1) vs += __shfl_xor(vs, off);
    float inv = rsqrtf(vs * (1.f / 512.f) + 1e-6f);
    const float* gp = gamma + lane * 8;
    const float* bp = beta + lane * 8;
    f32x4 g0 = *(const f32x4*)gp, g1 = *(const f32x4*)(gp + 4);
    f32x4 bb0 = *(const f32x4*)bp, bb1 = *(const f32x4*)(bp + 4);
    bf16x8 ov;
    #pragma unroll
    for (int j = 0; j < 4; j++) {
        ov[j]     = (__bf16)((v0[j] - mu) * inv * g0[j] + bb0[j]);
        ov[4 + j] = (__bf16)((v1[j] - mu) * inv * g1[j] + bb1[j]);
    }
    *(bf16x8*)(h + row * 512 + lane * 8) = ov;
}

// ---------------- transpose fp32 [K][N] -> bf16 [N][K], batched over z ----------------
__global__ void transpose_bf16(const float* __restrict__ in, __bf16* __restrict__ out,
                               int K, int N, size_t in_lstride, size_t out_lstride) {
    __shared__ float tile[32][33];
    in  += (size_t)blockIdx.z * in_lstride;
    out += (size_t)blockIdx.z * out_lstride;
    int n0 = blockIdx.x * 32, k0 = blockIdx.y * 32;
    int tx = threadIdx.x, ty = threadIdx.y;   // 32 x 8
    #pragma unroll
    for (int i = 0; i < 32; i += 8)
        tile[ty + i][tx] = in[(size_t)(k0 + ty + i) * N + n0 + tx];
    __syncthreads();
    #pragma unroll
    for (int i = 0; i < 32; i += 8)
        out[(size_t)(n0 + ty + i) * K + k0 + tx] = (__bf16)tile[tx][ty + i];
}

// ---------------- MFMA GEMM: C[M,N] = A[M,K](bf16) @ BT[N,K](bf16) ----------------
// R16-winning schedule ported: 256 x 128 tile, 1024 threads / 16 waves
// (4M x 4N, 64x32 out/wave), BK=64, 2-slot dbuf (96 KB, 1 block/CU),
// SINGLE barrier per body:
//   body s: vmcnt(0) [only stage(s) in flight, issued one full compute phase
//   earlier] -> barrier -> stage(s+1, OTHER buf) -> compute(s) [16 MFMA/wave].
// Staging: A 2 loads/thread + B 1 -> LPS=3 uniform. Swizzle for 128B rows:
// chunk ^= row&7. Epilogue: LDS restage -> full-line bf16x8 stores.
// EPI: 1 = qkv -> bf16 + phi on cols<1024; 3 = +bias,gelu,bf16.
template<int EPI, int K>
__global__ __launch_bounds__(1024) void gemm_bt(
    const __bf16* __restrict__ A, const __bf16* __restrict__ BT,
    __bf16* __restrict__ Cb, const float* __restrict__ bias, int N, int nbn) {
    constexpr int NT = K / 64;
    __shared__ __align__(16) __bf16 smem[2 * (256 + 128) * 64];   // 96 KB
    __bf16* Asm0 = smem;                    // 2 slots of 256*64
    __bf16* Bsm0 = smem + 2 * 256 * 64;     // 2 slots of 128*64
    const int t = threadIdx.x;              // 0..1023
    const int lane = t & 63;
    const int wave = t >> 6;                // 0..15
    const int wr = wave >> 2;               // 0..3 (M quarters of 64)
    const int wc = wave & 3;                // 0..3 (N quarters of 32)
    const int nblk = gridDim.x;
    const int q = nblk >> 3, r = nblk & 7;
    const int xcd = blockIdx.x & 7, loc = blockIdx.x >> 3;
    const int swz = (xcd < r ? xcd * (q + 1) : r * (q + 1) + (xcd - r) * q) + loc;
    const int m0 = (swz / nbn) * 256, n0 = (swz % nbn) * 128;   // n-fastest
    const int fr = lane & 15, fc = lane >> 4;

    // A: 256 rows x 8 chunks = 2048 slots (2/thread); B: 128 x 8 = 1024 (1/thread)
    const __bf16* Aps[2];
    int aslot[2];
    #pragma unroll
    for (int j = 0; j < 2; j++) {
        int slot = t + 1024 * j;
        int row = slot >> 3, cp = slot & 7;
        int sc = cp ^ (row & 7);
        Aps[j] = A + (size_t)(m0 + row) * K + sc * 8;
        aslot[j] = slot * 8;
    }
    const __bf16* Bp;
    int bslot;
    {
        int row = t >> 3, cp = t & 7;
        int sc = cp ^ (row & 7);
        Bp = BT + (size_t)(n0 + row) * K + sc * 8;
        bslot = t * 8;
    }

    f32x4 acc[4][2];
    #pragma unroll
    for (int m = 0; m < 4; m++)
        #pragma unroll
        for (int n = 0; n < 2; n++)
            acc[m][n] = (f32x4){0.f, 0.f, 0.f, 0.f};

    auto stage = [&](int koff, __bf16* Ad, __bf16* Bd) {
        GLOAD16(Aps[0] + koff, Ad + aslot[0]);
        GLOAD16(Aps[1] + koff, Ad + aslot[1]);
        GLOAD16(Bp + koff, Bd + bslot);
    };

    stage(0, Asm0, Bsm0);
    for (int s = 0; s < NT; s++) {
        asm volatile("s_waitcnt vmcnt(0)" ::: "memory");  // stage(s) resident
        __builtin_amdgcn_s_barrier();
        if (s + 1 < NT)
            stage((s + 1) * 64, Asm0 + ((s + 1) & 1) * 16384, Bsm0 + ((s + 1) & 1) * 8192);
        const __bf16* Ac = Asm0 + (s & 1) * 16384;
        const __bf16* Bc = Bsm0 + (s & 1) * 8192;
        #pragma unroll
        for (int kk = 0; kk < 2; kk++) {
            bf16x8 af[4], bfr[2];
            #pragma unroll
            for (int m = 0; m < 4; m++) {
                int ra = wr * 64 + m * 16 + fr;
                int c = kk * 4 + fc;
                af[m] = *(const bf16x8*)(Ac + ra * 64 + ((c ^ (ra & 7)) << 3));
            }
            #pragma unroll
            for (int n = 0; n < 2; n++) {
                int rb = wc * 32 + n * 16 + fr;
                int c = kk * 4 + fc;
                bfr[n] = *(const bf16x8*)(Bc + rb * 64 + ((c ^ (rb & 7)) << 3));
            }
            __builtin_amdgcn_s_setprio(1);
            #pragma unroll
            for (int m = 0; m < 4; m++)
                #pragma unroll
                for (int n = 0; n < 2; n++)
                    acc[m][n] = __builtin_amdgcn_mfma_f32_16x16x32_bf16(af[m], bfr[n], acc[m][n], 0, 0, 0);
            __builtin_amdgcn_s_setprio(0);
        }
    }

    // ---- epilogue: restage to LDS, then full-line coalesced stores ----
    const int cr = (lane >> 4) * 4;
    const int cc = lane & 15;
    __bf16* Cs = smem;                      // 256 x 136 = 68 KB (staging dead)
    __syncthreads();                        // all waves done reading staging
    #pragma unroll
    for (int m = 0; m < 4; m++) {
        #pragma unroll
        for (int n = 0; n < 2; n++) {
            #pragma unroll
            for (int r2 = 0; r2 < 4; r2++) {
                int lrow = wr * 64 + m * 16 + cr + r2;
                int lcol = wc * 32 + n * 16 + cc;
                float val = acc[m][n][r2];
                if (EPI == 1) {
                    if (n0 + lcol < 1024) val = fmaxf(val, 0.f) + 1e-3f;
                } else {
                    val = gelu_tanh(val + bias[n0 + lcol]);
                }
                Cs[lrow * 136 + lcol] = (__bf16)val;
            }
        }
    }
    __syncthreads();
    for (int i = t; i < 256 * 16; i += 1024) {
        int row = i >> 4, c8 = i & 15;
        bf16x8 v = *(const bf16x8*)(Cs + row * 136 + c8 * 8);
        *(bf16x8*)(Cb + (size_t)(m0 + row) * N + n0 + c8 * 8) = v;
    }
}

// ------- fused GEMM + residual + LayerNorm: full-row blocks (BN = 512) -------
// 1024 threads / 16 waves (2M x 8N, 32x64 out/wave), BK=64, 2-slot dbuf
// (144 KB), SINGLE barrier per step:
//   body s: vmcnt(0) -> barrier -> stage(s+1, OTHER buf) -> compute(s).
// Swizzle for 128B rows: chunk ^= row&7 (8 bank-groups).
template<int HASB, int K, int FINAL>
__global__ __launch_bounds__(1024) void gemm_ln(
    const __bf16* __restrict__ A, const __bf16* __restrict__ BT,
    const float* __restrict__ bias, float* __restrict__ x,
    const float* __restrict__ gamma, const float* __restrict__ beta,
    __bf16* __restrict__ hout, float* __restrict__ fout) {
    constexpr int NT = K / 64;
    __shared__ __align__(16) __bf16 smem[2 * 64 * 64 + 2 * 512 * 64];   // 16KB + 128KB
    __shared__ float sums[64][8][2];
    __shared__ float rowstat[64][2];
    __bf16* Aring = smem;                    // 2 slots of 64*64
    __bf16* Bring = smem + 2 * 64 * 64;      // 2 slots of 512*64
    const int t = threadIdx.x;               // 0..1023
    const int lane = t & 63;
    const int wave = t >> 6;                 // 0..15
    const int wr = wave >> 3;                // 0..1 (row half, 32 rows)
    const int wc = wave & 7;                 // 0..7 (col group of 64)
    const int m0 = blockIdx.x * 64;
    const int fr = lane & 15, fc = lane >> 4;

    // A: 64 rows x 8 chunks = 512 slots (t<512: 1 each)
    const __bf16* Ap = A;
    int aslot = 0;
    if (t < 512) {
        int row = t >> 3, cp = t & 7;
        int sc = cp ^ (row & 7);
        Ap = A + (size_t)(m0 + row) * K + sc * 8;
        aslot = t * 8;
    }
    // B: 512 rows x 8 chunks = 4096 slots (4/thread)
    const __bf16* Bps[4];
    int bslot[4];
    #pragma unroll
    for (int j = 0; j < 4; j++) {
        int slot = t + 1024 * j;
        int row = slot >> 3, cp = slot & 7;
        int sc = cp ^ (row & 7);
        Bps[j] = BT + (size_t)row * K + sc * 8;
        bslot[j] = slot * 8;
    }
    auto stage = [&](int ss) {
        int sl = ss & 1;
        #pragma unroll
        for (int j = 0; j < 4; j++) GLOAD16(Bps[j] + ss * 64, Bring + sl * 32768 + bslot[j]);
        if (t < 512) GLOAD16(Ap + ss * 64, Aring + sl * 4096 + aslot);
    };

    f32x4 acc[2][4];
    #pragma unroll
    for (int m = 0; m < 2; m++)
        #pragma unroll
        for (int n = 0; n < 4; n++)
            acc[m][n] = (f32x4){0.f, 0.f, 0.f, 0.f};

    stage(0);
    for (int s = 0; s < NT; s++) {
        asm volatile("s_waitcnt vmcnt(0)" ::: "memory");  // stage(s) resident
        __builtin_amdgcn_s_barrier();
        if (s + 1 < NT) stage(s + 1);                     // other buf, flies under compute(s)
        const __bf16* Ac = Aring + (s & 1) * 4096;
        const __bf16* Bc = Bring + (s & 1) * 32768;
        #pragma unroll
        for (int kk = 0; kk < 2; kk++) {
            bf16x8 af[2], bfr[4];
            #pragma unroll
            for (int m = 0; m < 2; m++) {
                int ra = wr * 32 + m * 16 + fr;
                int c = kk * 4 + fc;
                af[m] = *(const bf16x8*)(Ac + ra * 64 + ((c ^ (ra & 7)) << 3));
            }
            #pragma unroll
            for (int n = 0; n < 4; n++) {
                int rb = wc * 64 + n * 16 + fr;
                int c = kk * 4 + fc;
                bfr[n] = *(const bf16x8*)(Bc + rb * 64 + ((c ^ (rb & 7)) << 3));
            }
            __builtin_amdgcn_s_setprio(1);
            #pragma unroll
            for (int m = 0; m < 2; m++)
                #pragma unroll
                for (int n = 0; n < 4; n++)
                    acc[m][n] = __builtin_amdgcn_mfma_f32_16x16x32_bf16(af[m], bfr[n], acc[m][n], 0, 0, 0);
            __builtin_amdgcn_s_setprio(0);
        }
    }

    // ---- epilogue: residual + LN over the full row (512 cols in-block) ----
    const int cr = (lane >> 4) * 4;
    const int cc = lane & 15;
    float bia[4], gam[4], bet[4];
    #pragma unroll
    for (int n = 0; n < 4; n++) {
        int gcol = wc * 64 + n * 16 + cc;
        bia[n] = HASB ? bias[gcol] : 0.f;
        gam[n] = gamma[gcol];
        bet[n] = beta[gcol];
    }
    float xn[2][4][4];
    #pragma unroll
    for (int m = 0; m < 2; m++) {
        #pragma unroll
        for (int r2 = 0; r2 < 4; r2++) {
            int grow = m0 + wr * 32 + m * 16 + cr + r2;
            #pragma unroll
            for (int n = 0; n < 4; n++) {
                int gcol = wc * 64 + n * 16 + cc;
                xn[m][n][r2] = acc[m][n][r2] + bia[n] + x[(size_t)grow * 512 + gcol];
            }
        }
    }
    #pragma unroll
    for (int m = 0; m < 2; m++) {
        #pragma unroll
        for (int r2 = 0; r2 < 4; r2++) {
            float s1 = 0.f, q1 = 0.f;
            #pragma unroll
            for (int n = 0; n < 4; n++) { float v = xn[m][n][r2]; s1 += v; q1 += v * v; }
            #pragma unroll
            for (int off = 1; off <= 8; off <<= 1) {
                s1 += __shfl_xor(s1, off);
                q1 += __shfl_xor(q1, off);
            }
            if (cc == 0) {
                int rl = wr * 32 + m * 16 + cr + r2;
                sums[rl][wc][0] = s1;
                sums[rl][wc][1] = q1;
            }
        }
    }
    __syncthreads();
    if (t < 64) {
        float S = 0.f, Q = 0.f;
        #pragma unroll
        for (int w = 0; w < 8; w++) { S += sums[t][w][0]; Q += sums[t][w][1]; }
        float mu = S * (1.f / 512.f);
        float var = Q * (1.f / 512.f) - mu * mu;
        rowstat[t][0] = mu;
        rowstat[t][1] = rsqrtf(var + 1e-6f);
    }
    __syncthreads();
    __bf16* Hs = smem;                      // 64 x 520 (staging dead)
    #pragma unroll
    for (int m = 0; m < 2; m++) {
        #pragma unroll
        for (int r2 = 0; r2 < 4; r2++) {
            int rl = wr * 32 + m * 16 + cr + r2;
            int grow = m0 + rl;
            float mu = rowstat[rl][0], inv = rowstat[rl][1];
            #pragma unroll
            for (int n = 0; n < 4; n++) {
                int gcol = wc * 64 + n * 16 + cc;
                float v = xn[m][n][r2];
                float hv = (v - mu) * inv * gam[n] + bet[n];
                if (!FINAL) {
                    x[(size_t)grow * 512 + gcol] = v;   // RMW line: already resident
                    Hs[rl * 520 + gcol] = (__bf16)hv;
                } else {
                    fout[(size_t)grow * 512 + gcol] = hv;
                }
            }
        }
    }
    if (!FINAL) {
        __syncthreads();
        for (int i = t; i < 64 * 64; i += 1024) {
            int row = i >> 6, c8 = i & 63;
            bf16x8 v = *(const bf16x8*)(Hs + row * 520 + c8 * 8);
            *(bf16x8*)(hout + (size_t)(m0 + row) * 512 + c8 * 8) = v;
        }
    }
}

// ---------------- kv partial: per (b,h,chunk of 64 rows) 64x64 + pksum ----------------
__global__ __launch_bounds__(256) void kv_partial(const __bf16* __restrict__ qkvb,
                                                  float* __restrict__ part) {
    int bh = blockIdx.x;           // 32
    int chunk = blockIdx.y;        // 64 chunks of 64 rows
    int b = bh >> 3, hh = bh & 7;
    int t = threadIdx.x;
    int f = t & 63, eg = t >> 6;   // e-base = eg*16
    size_t base = ((size_t)b * SEQ + (size_t)chunk * 64) * 1536;
    const __bf16* kcol = qkvb + base + 512 + hh * 64 + f;
    const __bf16* vrow = qkvb + base + 1024 + hh * 64 + eg * 16;
    float psum = 0.f;
    f32x4 a0 = {0.f,0.f,0.f,0.f}, a1 = a0, a2 = a0, a3 = a0;
    for (int s = 0; s < 64; s++) {
        size_t o = (size_t)s * 1536;
        float pk = (float)kcol[o];
        psum += pk;
        bf16x8 w0 = *(const bf16x8*)(vrow + o);
        bf16x8 w1 = *(const bf16x8*)(vrow + o + 8);
        #pragma unroll
        for (int j = 0; j < 4; j++) {
            a0[j] += (float)w0[j]     * pk;
            a1[j] += (float)w0[4 + j] * pk;
            a2[j] += (float)w1[j]     * pk;
            a3[j] += (float)w1[4 + j] * pk;
        }
    }
    float* dst = part + ((size_t)chunk * 32 + bh) * 4160 + (size_t)f * 65 + eg * 16;
    #pragma unroll
    for (int j = 0; j < 4; j++) { dst[j] = a0[j]; dst[4+j] = a1[j]; dst[8+j] = a2[j]; dst[12+j] = a3[j]; }
    if (eg == 0) dst[64] = psum;   // pksum slot
}

__global__ void kv_reduce(const float* __restrict__ part, float* __restrict__ kvfin) {
    int i = blockIdx.x * 256 + threadIdx.x;
    if (i >= 32 * 4160) return;
    float s = 0.f;
    #pragma unroll 8
    for (int c = 0; c < 64; c++) s += part[(size_t)c * (32 * 4160) + i];
    kvfin[i] = s;
}

// ---------------- num / den / divide -> attn (bf16), MFMA with den column ----
__global__ __launch_bounds__(256) void num_attn(const __bf16* __restrict__ qkvb,
                                                const float* __restrict__ kvfin,
                                                __bf16* __restrict__ attn) {
    __shared__ __bf16 kvb[64][86];
    __shared__ __bf16 cs[128][72];
    int bh = blockIdx.x, chunk = blockIdx.y;   // 32 x 32
    int b = bh >> 3, hh = bh & 7;
    const float* src = kvfin + (size_t)bh * 4160;
    int t = threadIdx.x;
    for (int i = t; i < 4096; i += 256) {
        int f = i >> 6, e = i & 63;
        kvb[f][e] = (__bf16)src[f * 65 + e];
    }
    if (t < 64) {
        kvb[t][64] = (__bf16)src[t * 65 + 64];     // ps column
        #pragma unroll
        for (int e = 65; e < 80; e++) kvb[t][e] = (__bf16)0.f;
    }
    const int lane = t & 63, w = t >> 6;
    const int fr = lane & 15, fc = lane >> 4;
    size_t rowbase = (size_t)b * SEQ + (size_t)chunk * 128 + w * 32;
    bf16x8 a[2][2];
    #pragma unroll
    for (int rt = 0; rt < 2; rt++)
        #pragma unroll
        for (int ks = 0; ks < 2; ks++)
            a[rt][ks] = *(const bf16x8*)(qkvb + (rowbase + rt * 16 + fr) * 1536 + hh * 64 + ks * 32 + fc * 8);
    __syncthreads();   // kvb visible
    bf16x8 bfrag[5][2];
    #pragma unroll
    for (int n = 0; n < 5; n++)
        #pragma unroll
        for (int ks = 0; ks < 2; ks++) {
            bf16x8 bv;
            #pragma unroll
            for (int j = 0; j < 8; j++) bv[j] = kvb[ks * 32 + fc * 8 + j][n * 16 + fr];
            bfrag[n][ks] = bv;
        }
    f32x4 acc[2][5];
    #pragma unroll
    for (int rt = 0; rt < 2; rt++)
        #pragma unroll
        for (int n = 0; n < 5; n++)
            acc[rt][n] = (f32x4){0.f, 0.f, 0.f, 0.f};
    #pragma unroll
    for (int ks = 0; ks < 2; ks++)
        #pragma unroll
        for (int rt = 0; rt < 2; rt++)
            #pragma unroll
            for (int n = 0; n < 5; n++)
                acc[rt][n] = __builtin_amdgcn_mfma_f32_16x16x32_bf16(a[rt][ks], bfrag[n][ks], acc[rt][n], 0, 0, 0);
    const int cr = (lane >> 4) * 4, cc = lane & 15;
    #pragma unroll
    for (int rt = 0; rt < 2; rt++) {
        float rdv[4];
        #pragma unroll
        for (int r2 = 0; r2 < 4; r2++)
            rdv[r2] = 1.f / __shfl(acc[rt][4][r2], lane & 48);   // den from cc==0 lane
        #pragma unroll
        for (int r2 = 0; r2 < 4; r2++) {
            int lr = w * 32 + rt * 16 + cr + r2;
            #pragma unroll
            for (int n = 0; n < 4; n++)
                cs[lr][n * 16 + cc] = (__bf16)(acc[rt][n][r2] * rdv[r2]);
        }
    }
    __syncthreads();
    size_t base = (size_t)b * SEQ + (size_t)chunk * 128;
    for (int i = t; i < 128 * 8; i += 256) {
        int row = i >> 3, c8 = i & 7;
        bf16x8 v = *(const bf16x8*)(&cs[row][c8 * 8]);
        *(bf16x8*)(attn + (base + row) * 512 + hh * 64 + c8 * 8) = v;
    }
}

extern "C" void kernel_launch(void* const* d_in, const int* in_sizes, int n_in,
                              void* d_out, int out_size, void* d_ws, size_t ws_size,
                              hipStream_t stream) {
    const int*   tokens = (const int*)d_in[0];
    const float* embed  = (const float*)d_in[1];
    const float* Wq     = (const float*)d_in[2];
    const float* Wk     = (const float*)d_in[3];
    const float* Wv     = (const float*)d_in[4];
    const float* Wo     = (const float*)d_in[5];
    const float* ln1_s  = (const float*)d_in[6];
    const float* ln1_b  = (const float*)d_in[7];
    const float* W1     = (const float*)d_in[8];
    const float* b1     = (const float*)d_in[9];
    const float* W2     = (const float*)d_in[10];
    const float* b2     = (const float*)d_in[11];
    const float* ln2_s  = (const float*)d_in[12];
    const float* ln2_b  = (const float*)d_in[13];
    const float* lnf_s  = (const float*)d_in[14];
    const float* lnf_b  = (const float*)d_in[15];
    float* out = (float*)d_out;

    float* ws = (float*)d_ws;
    size_t off = 0;
    float* pos = ws;               off += 2097152;            // 4096*512 f32
    float* x   = ws + off;         off += 8388608;            // 16384*512 f32
    __bf16* h    = (__bf16*)(ws + off); off += 4194304;       // 16384*512 bf16
    __bf16* attn = (__bf16*)(ws + off); off += 4194304;       // 16384*512 bf16
    __bf16* qkvb = (__bf16*)(ws + off);                       // 16384*1536 bf16
    __bf16* hid  = (__bf16*)(ws + off); off += 16777216;      // 16384*2048 bf16 (union, serialized)
    float* kvpart = ws + off;      off += 64 * 32 * 4160;     // partials (64 chunks)
    float* kvfin  = ws + off;      off += 32 * 4160;
    __bf16* wbuf  = (__bf16*)(ws + off);                      // 6 * 3145728 bf16

    pos_kernel<<<4096, 256, 0, stream>>>(pos);
    transpose_bf16<<<dim3(16, 16, 6), dim3(32, 8), 0, stream>>>(Wq, wbuf,          512, 512,  262144, 3145728);
    transpose_bf16<<<dim3(16, 16, 6), dim3(32, 8), 0, stream>>>(Wk, wbuf + 262144, 512, 512,  262144, 3145728);
    transpose_bf16<<<dim3(16, 16, 6), dim3(32, 8), 0, stream>>>(Wv, wbuf + 524288, 512, 512,  262144, 3145728);
    transpose_bf16<<<dim3(16, 16, 6), dim3(32, 8), 0, stream>>>(Wo, wbuf + 786432, 512, 512,  262144, 3145728);
    transpose_bf16<<<dim3(64, 16, 6), dim3(32, 8), 0, stream>>>(W1, wbuf + 1048576, 512, 2048, 1048576, 3145728);
    transpose_bf16<<<dim3(16, 64, 6), dim3(32, 8), 0, stream>>>(W2, wbuf + 2097152, 2048, 512, 1048576, 3145728);
    embed_ln<<<4096, 256, 0, stream>>>(tokens, embed, pos, ln1_s, ln1_b, x, h);

    for (int l = 0; l < 6; l++) {
        const __bf16* wl = wbuf + (size_t)l * 3145728;
        gemm_bt<1, 512><<<768, 1024, 0, stream>>>(h, wl, qkvb, nullptr, 1536, 12);
        kv_partial<<<dim3(32, 64), 256, 0, stream>>>(qkvb, kvpart);
        kv_reduce<<<520, 256, 0, stream>>>(kvpart, kvfin);
        num_attn<<<dim3(32, 32), 256, 0, stream>>>(qkvb, kvfin, attn);
        // Wo + residual + LN2 fused
        gemm_ln<0, 512, 0><<<256, 1024, 0, stream>>>(attn, wl + 786432, nullptr, x,
                                                     ln2_s + l * 512, ln2_b + l * 512, h, nullptr);
        gemm_bt<3, 512><<<1024, 1024, 0, stream>>>(h, wl + 1048576, hid, b1 + (size_t)l * 2048, 2048, 16);
        // MLP2 + bias + residual + LN1(next) / LNf fused
        if (l < 5) {
            gemm_ln<1, 2048, 0><<<256, 1024, 0, stream>>>(hid, wl + 2097152, b2 + (size_t)l * 512, x,
                                                          ln1_s + (l + 1) * 512, ln1_b + (l + 1) * 512, h, nullptr);
        } else {
            gemm_ln<1, 2048, 1><<<256, 1024, 0, stream>>>(hid, wl + 2097152, b2 + (size_t)l * 512, x,
                                                          lnf_s, lnf_b, nullptr, out);
        }
    }
}

// Round 19
// 1440.104 us; speedup vs baseline: 1.0503x; 1.0503x over previous
//
#include <hip/hip_runtime.h>

typedef float f32x4 __attribute__((ext_vector_type(4)));
typedef __bf16 bf16x8 __attribute__((ext_vector_type(8)));

#define NROWS 16384   // B*S
#define SEQ   4096
#define EMBD  512
#define MLPD  2048

__device__ inline float gelu_tanh(float x) {
    float t = 0.7978845608028654f * (x + 0.044715f * x * x * x);
    float e = __expf(2.f * t);
    float th = 1.f - 2.f / (1.f + e);
    return 0.5f * x * (1.f + th);
}

// direct global->LDS 16B DMA; LDS dest must be linear in lane order
#define GLOAD16(gp, lp)                                                        \
    __builtin_amdgcn_global_load_lds(                                          \
        (const __attribute__((address_space(1))) void*)(gp),                   \
        (__attribute__((address_space(3))) void*)(lp), 16, 0, 0)

// ---------------- positional table: pos[s][512] ----------------
__global__ void pos_kernel(float* __restrict__ pos) {
    int i = blockIdx.x * 256 + threadIdx.x;        // 4096*256
    int s = i >> 8, j = i & 255;
    float div = __expf((float)j * (-2.f * 9.210340371976184f / 512.f));
    float a = (float)s * div;
    pos[(size_t)s * 512 + 2 * j]     = sinf(a);
    pos[(size_t)s * 512 + 2 * j + 1] = cosf(a);
}

// ---------------- embedding gather + pos add + LN(layer0) ----------------
__global__ __launch_bounds__(256) void embed_ln(
    const int* __restrict__ tokens, const float* __restrict__ embed,
    const float* __restrict__ pos, const float* __restrict__ gamma,
    const float* __restrict__ beta, float* __restrict__ x,
    __bf16* __restrict__ h) {
    int lane = threadIdx.x & 63;
    size_t row = (size_t)blockIdx.x * 4 + (threadIdx.x >> 6);
    int s = (int)(row & (SEQ - 1));
    int tok = tokens[row];
    const float* ep = embed + (size_t)tok * 512 + lane * 8;
    const float* pp = pos + (size_t)s * 512 + lane * 8;
    f32x4 v0 = *(const f32x4*)ep + *(const f32x4*)pp;
    f32x4 v1 = *(const f32x4*)(ep + 4) + *(const f32x4*)(pp + 4);
    *(f32x4*)(x + row * 512 + lane * 8) = v0;
    *(f32x4*)(x + row * 512 + lane * 8 + 4) = v1;
    float sum = (v0[0] + v0[1]) + (v0[2] + v0[3]) + (v1[0] + v1[1]) + (v1[2] + v1[3]);
    #pragma unroll
    for (int off = 32; off; off >>= 1) sum += __shfl_xor(sum, off);
    float mu = sum * (1.f / 512.f);
    float vs = 0.f;
    #pragma unroll
    for (int j = 0; j < 4; j++) {
        float d0 = v0[j] - mu; vs += d0 * d0;
        float d1 = v1[j] - mu; vs += d1 * d1;
    }
    #pragma unroll
    for (int off = 32; off; off >>= 1) vs += __shfl_xor(vs, off);
    float inv = rsqrtf(vs * (1.f / 512.f) + 1e-6f);
    const float* gp = gamma + lane * 8;
    const float* bp = beta + lane * 8;
    f32x4 g0 = *(const f32x4*)gp, g1 = *(const f32x4*)(gp + 4);
    f32x4 bb0 = *(const f32x4*)bp, bb1 = *(const f32x4*)(bp + 4);
    bf16x8 ov;
    #pragma unroll
    for (int j = 0; j < 4; j++) {
        ov[j]     = (__bf16)((v0[j] - mu) * inv * g0[j] + bb0[j]);
        ov[4 + j] = (__bf16)((v1[j] - mu) * inv * g1[j] + bb1[j]);
    }
    *(bf16x8*)(h + row * 512 + lane * 8) = ov;
}

// ---------------- transpose fp32 [K][N] -> bf16 [N][K], batched over z ----------------
__global__ void transpose_bf16(const float* __restrict__ in, __bf16* __restrict__ out,
                               int K, int N, size_t in_lstride, size_t out_lstride) {
    __shared__ float tile[32][33];
    in  += (size_t)blockIdx.z * in_lstride;
    out += (size_t)blockIdx.z * out_lstride;
    int n0 = blockIdx.x * 32, k0 = blockIdx.y * 32;
    int tx = threadIdx.x, ty = threadIdx.y;   // 32 x 8
    #pragma unroll
    for (int i = 0; i < 32; i += 8)
        tile[ty + i][tx] = in[(size_t)(k0 + ty + i) * N + n0 + tx];
    __syncthreads();
    #pragma unroll
    for (int i = 0; i < 32; i += 8)
        out[(size_t)(n0 + ty + i) * K + k0 + tx] = (__bf16)tile[tx][ty + i];
}

// ---------------- MFMA GEMM: C[M,N] = A[M,K](bf16) @ BT[N,K](bf16) ----------------
// R17-best: 256 x 128 tile, 512 threads / 8 waves (4M x 2N, 64x64 out/wave),
// BK=32, 3-slot LDS ring (72 KB -> 2 blocks/CU), SINGLE barrier/step, counted
// vmcnt(3). Epilogue: LDS restage -> full-line bf16x8 stores.
// EPI: 1 = qkv -> bf16 + phi on cols<1024; 3 = +bias,gelu,bf16.
template<int EPI, int K>
__global__ __launch_bounds__(512, 4) void gemm_bt(
    const __bf16* __restrict__ A, const __bf16* __restrict__ BT,
    __bf16* __restrict__ Cb, const float* __restrict__ bias, int N, int nbn) {
    constexpr int NT = K / 32;
    __shared__ __align__(16) __bf16 smem[3 * (256 + 128) * 32];   // 72 KB
    __bf16* Asm0 = smem;                    // 3 slots of 256*32
    __bf16* Bsm0 = smem + 3 * 256 * 32;     // 3 slots of 128*32
    const int t = threadIdx.x;
    const int lane = t & 63;
    const int wave = t >> 6;
    const int wr = wave >> 1, wc = wave & 1;
    const int nblk = gridDim.x;
    const int q = nblk >> 3, r = nblk & 7;
    const int xcd = blockIdx.x & 7, loc = blockIdx.x >> 3;
    const int swz = (xcd < r ? xcd * (q + 1) : r * (q + 1) + (xcd - r) * q) + loc;
    const int m0 = (swz / nbn) * 256, n0 = (swz % nbn) * 128;   // n-fastest
    const int fr = lane & 15, fc = lane >> 4;

    // A: 1024 slots (2/thread); B: 512 slots (1/thread)
    const __bf16* Aps[2];
    int aslot[2];
    #pragma unroll
    for (int j = 0; j < 2; j++) {
        int slot = t + 512 * j;
        int row = slot >> 2, cp = slot & 3;
        int sc = cp ^ ((row >> 1) & 3);
        Aps[j] = A + (size_t)(m0 + row) * K + sc * 8;
        aslot[j] = slot * 8;
    }
    const __bf16* Bp;
    int bslot;
    {
        int row = t >> 2, cp = t & 3;
        int sc = cp ^ ((row >> 1) & 3);
        Bp = BT + (size_t)(n0 + row) * K + sc * 8;
        bslot = t * 8;
    }

    f32x4 acc[4][4];
    #pragma unroll
    for (int m = 0; m < 4; m++)
        #pragma unroll
        for (int n = 0; n < 4; n++)
            acc[m][n] = (f32x4){0.f, 0.f, 0.f, 0.f};

    auto stage = [&](int koff, __bf16* Ad, __bf16* Bd) {
        GLOAD16(Aps[0] + koff, Ad + aslot[0]);
        GLOAD16(Aps[1] + koff, Ad + aslot[1]);
        GLOAD16(Bp + koff, Bd + bslot);
    };

    stage(0, Asm0, Bsm0);
    stage(32, Asm0 + 256 * 32, Bsm0 + 128 * 32);

    for (int s = 0; s < NT; s++) {
        if (s + 1 < NT) {
            asm volatile("s_waitcnt vmcnt(3)" ::: "memory");   // slot s landed
        } else {
            asm volatile("s_waitcnt vmcnt(0)" ::: "memory");
        }
        __builtin_amdgcn_s_barrier();
        if (s + 2 < NT) {
            int sl = (s + 2) % 3;
            stage((s + 2) * 32, Asm0 + sl * 256 * 32, Bsm0 + sl * 128 * 32);
        }
        const __bf16* Ac = Asm0 + (s % 3) * 256 * 32;
        const __bf16* Bc = Bsm0 + (s % 3) * 128 * 32;

        bf16x8 af[4], bfr[4];
        #pragma unroll
        for (int m = 0; m < 4; m++) {
            int ra = wr * 64 + m * 16 + fr;
            af[m] = *(const bf16x8*)(Ac + ra * 32 + ((fc ^ ((ra >> 1) & 3)) << 3));
        }
        #pragma unroll
        for (int n = 0; n < 4; n++) {
            int rb = wc * 64 + n * 16 + fr;
            bfr[n] = *(const bf16x8*)(Bc + rb * 32 + ((fc ^ ((rb >> 1) & 3)) << 3));
        }
        __builtin_amdgcn_s_setprio(1);
        #pragma unroll
        for (int m = 0; m < 4; m++)
            #pragma unroll
            for (int n = 0; n < 4; n++)
                acc[m][n] = __builtin_amdgcn_mfma_f32_16x16x32_bf16(af[m], bfr[n], acc[m][n], 0, 0, 0);
        __builtin_amdgcn_s_setprio(0);
    }

    // ---- epilogue: restage to LDS, then full-line coalesced stores ----
    const int cr = (lane >> 4) * 4;
    const int cc = lane & 15;
    __bf16* Cs = smem;                      // 256 x 136 = 68 KB (staging dead)
    __syncthreads();                        // all waves done reading staging
    #pragma unroll
    for (int m = 0; m < 4; m++) {
        #pragma unroll
        for (int n = 0; n < 4; n++) {
            #pragma unroll
            for (int r2 = 0; r2 < 4; r2++) {
                int lrow = wr * 64 + m * 16 + cr + r2;
                int lcol = wc * 64 + n * 16 + cc;
                float val = acc[m][n][r2];
                if (EPI == 1) {
                    if (n0 + lcol < 1024) val = fmaxf(val, 0.f) + 1e-3f;
                } else {
                    val = gelu_tanh(val + bias[n0 + lcol]);
                }
                Cs[lrow * 136 + lcol] = (__bf16)val;
            }
        }
    }
    __syncthreads();
    for (int i = t; i < 256 * 16; i += 512) {
        int row = i >> 4, c8 = i & 15;
        bf16x8 v = *(const bf16x8*)(Cs + row * 136 + c8 * 8);
        *(bf16x8*)(Cb + (size_t)(m0 + row) * N + n0 + c8 * 8) = v;
    }
}

// ------- fused GEMM + residual + LayerNorm: full-row blocks (BN = 512) -------
// 1024 threads / 16 waves (2M x 8N, 32x64 out/wave), BK=64, 2-slot dbuf
// (144 KB), SINGLE barrier per step:
//   body s: vmcnt(0) -> barrier -> stage(s+1, OTHER buf) -> compute(s).
// Swizzle for 128B rows: chunk ^= row&7 (8 bank-groups).
template<int HASB, int K, int FINAL>
__global__ __launch_bounds__(1024) void gemm_ln(
    const __bf16* __restrict__ A, const __bf16* __restrict__ BT,
    const float* __restrict__ bias, float* __restrict__ x,
    const float* __restrict__ gamma, const float* __restrict__ beta,
    __bf16* __restrict__ hout, float* __restrict__ fout) {
    constexpr int NT = K / 64;
    __shared__ __align__(16) __bf16 smem[2 * 64 * 64 + 2 * 512 * 64];   // 16KB + 128KB
    __shared__ float sums[64][8][2];
    __shared__ float rowstat[64][2];
    __bf16* Aring = smem;                    // 2 slots of 64*64
    __bf16* Bring = smem + 2 * 64 * 64;      // 2 slots of 512*64
    const int t = threadIdx.x;               // 0..1023
    const int lane = t & 63;
    const int wave = t >> 6;                 // 0..15
    const int wr = wave >> 3;                // 0..1 (row half, 32 rows)
    const int wc = wave & 7;                 // 0..7 (col group of 64)
    const int m0 = blockIdx.x * 64;
    const int fr = lane & 15, fc = lane >> 4;

    // A: 64 rows x 8 chunks = 512 slots (t<512: 1 each)
    const __bf16* Ap = A;
    int aslot = 0;
    if (t < 512) {
        int row = t >> 3, cp = t & 7;
        int sc = cp ^ (row & 7);
        Ap = A + (size_t)(m0 + row) * K + sc * 8;
        aslot = t * 8;
    }
    // B: 512 rows x 8 chunks = 4096 slots (4/thread)
    const __bf16* Bps[4];
    int bslot[4];
    #pragma unroll
    for (int j = 0; j < 4; j++) {
        int slot = t + 1024 * j;
        int row = slot >> 3, cp = slot & 7;
        int sc = cp ^ (row & 7);
        Bps[j] = BT + (size_t)row * K + sc * 8;
        bslot[j] = slot * 8;
    }
    auto stage = [&](int ss) {
        int sl = ss & 1;
        #pragma unroll
        for (int j = 0; j < 4; j++) GLOAD16(Bps[j] + ss * 64, Bring + sl * 32768 + bslot[j]);
        if (t < 512) GLOAD16(Ap + ss * 64, Aring + sl * 4096 + aslot);
    };

    f32x4 acc[2][4];
    #pragma unroll
    for (int m = 0; m < 2; m++)
        #pragma unroll
        for (int n = 0; n < 4; n++)
            acc[m][n] = (f32x4){0.f, 0.f, 0.f, 0.f};

    stage(0);
    for (int s = 0; s < NT; s++) {
        asm volatile("s_waitcnt vmcnt(0)" ::: "memory");  // stage(s) resident
        __builtin_amdgcn_s_barrier();
        if (s + 1 < NT) stage(s + 1);                     // other buf, flies under compute(s)
        const __bf16* Ac = Aring + (s & 1) * 4096;
        const __bf16* Bc = Bring + (s & 1) * 32768;
        #pragma unroll
        for (int kk = 0; kk < 2; kk++) {
            bf16x8 af[2], bfr[4];
            #pragma unroll
            for (int m = 0; m < 2; m++) {
                int ra = wr * 32 + m * 16 + fr;
                int c = kk * 4 + fc;
                af[m] = *(const bf16x8*)(Ac + ra * 64 + ((c ^ (ra & 7)) << 3));
            }
            #pragma unroll
            for (int n = 0; n < 4; n++) {
                int rb = wc * 64 + n * 16 + fr;
                int c = kk * 4 + fc;
                bfr[n] = *(const bf16x8*)(Bc + rb * 64 + ((c ^ (rb & 7)) << 3));
            }
            __builtin_amdgcn_s_setprio(1);
            #pragma unroll
            for (int m = 0; m < 2; m++)
                #pragma unroll
                for (int n = 0; n < 4; n++)
                    acc[m][n] = __builtin_amdgcn_mfma_f32_16x16x32_bf16(af[m], bfr[n], acc[m][n], 0, 0, 0);
            __builtin_amdgcn_s_setprio(0);
        }
    }

    // ---- epilogue: residual + LN over the full row (512 cols in-block) ----
    const int cr = (lane >> 4) * 4;
    const int cc = lane & 15;
    float bia[4], gam[4], bet[4];
    #pragma unroll
    for (int n = 0; n < 4; n++) {
        int gcol = wc * 64 + n * 16 + cc;
        bia[n] = HASB ? bias[gcol] : 0.f;
        gam[n] = gamma[gcol];
        bet[n] = beta[gcol];
    }
    float xn[2][4][4];
    #pragma unroll
    for (int m = 0; m < 2; m++) {
        #pragma unroll
        for (int r2 = 0; r2 < 4; r2++) {
            int grow = m0 + wr * 32 + m * 16 + cr + r2;
            #pragma unroll
            for (int n = 0; n < 4; n++) {
                int gcol = wc * 64 + n * 16 + cc;
                xn[m][n][r2] = acc[m][n][r2] + bia[n] + x[(size_t)grow * 512 + gcol];
            }
        }
    }
    #pragma unroll
    for (int m = 0; m < 2; m++) {
        #pragma unroll
        for (int r2 = 0; r2 < 4; r2++) {
            float s1 = 0.f, q1 = 0.f;
            #pragma unroll
            for (int n = 0; n < 4; n++) { float v = xn[m][n][r2]; s1 += v; q1 += v * v; }
            #pragma unroll
            for (int off = 1; off <= 8; off <<= 1) {
                s1 += __shfl_xor(s1, off);
                q1 += __shfl_xor(q1, off);
            }
            if (cc == 0) {
                int rl = wr * 32 + m * 16 + cr + r2;
                sums[rl][wc][0] = s1;
                sums[rl][wc][1] = q1;
            }
        }
    }
    __syncthreads();
    if (t < 64) {
        float S = 0.f, Q = 0.f;
        #pragma unroll
        for (int w = 0; w < 8; w++) { S += sums[t][w][0]; Q += sums[t][w][1]; }
        float mu = S * (1.f / 512.f);
        float var = Q * (1.f / 512.f) - mu * mu;
        rowstat[t][0] = mu;
        rowstat[t][1] = rsqrtf(var + 1e-6f);
    }
    __syncthreads();
    __bf16* Hs = smem;                      // 64 x 520 (staging dead)
    #pragma unroll
    for (int m = 0; m < 2; m++) {
        #pragma unroll
        for (int r2 = 0; r2 < 4; r2++) {
            int rl = wr * 32 + m * 16 + cr + r2;
            int grow = m0 + rl;
            float mu = rowstat[rl][0], inv = rowstat[rl][1];
            #pragma unroll
            for (int n = 0; n < 4; n++) {
                int gcol = wc * 64 + n * 16 + cc;
                float v = xn[m][n][r2];
                float hv = (v - mu) * inv * gam[n] + bet[n];
                if (!FINAL) {
                    x[(size_t)grow * 512 + gcol] = v;   // RMW line: already resident
                    Hs[rl * 520 + gcol] = (__bf16)hv;
                } else {
                    fout[(size_t)grow * 512 + gcol] = hv;
                }
            }
        }
    }
    if (!FINAL) {
        __syncthreads();
        for (int i = t; i < 64 * 64; i += 1024) {
            int row = i >> 6, c8 = i & 63;
            bf16x8 v = *(const bf16x8*)(Hs + row * 520 + c8 * 8);
            *(bf16x8*)(hout + (size_t)(m0 + row) * 512 + c8 * 8) = v;
        }
    }
}

// ---------------- kv partial: per (b,h,chunk of 64 rows) 64x64 + pksum ----------------
__global__ __launch_bounds__(256) void kv_partial(const __bf16* __restrict__ qkvb,
                                                  float* __restrict__ part) {
    int bh = blockIdx.x;           // 32
    int chunk = blockIdx.y;        // 64 chunks of 64 rows
    int b = bh >> 3, hh = bh & 7;
    int t = threadIdx.x;
    int f = t & 63, eg = t >> 6;   // e-base = eg*16
    size_t base = ((size_t)b * SEQ + (size_t)chunk * 64) * 1536;
    const __bf16* kcol = qkvb + base + 512 + hh * 64 + f;
    const __bf16* vrow = qkvb + base + 1024 + hh * 64 + eg * 16;
    float psum = 0.f;
    f32x4 a0 = {0.f,0.f,0.f,0.f}, a1 = a0, a2 = a0, a3 = a0;
    for (int s = 0; s < 64; s++) {
        size_t o = (size_t)s * 1536;
        float pk = (float)kcol[o];
        psum += pk;
        bf16x8 w0 = *(const bf16x8*)(vrow + o);
        bf16x8 w1 = *(const bf16x8*)(vrow + o + 8);
        #pragma unroll
        for (int j = 0; j < 4; j++) {
            a0[j] += (float)w0[j]     * pk;
            a1[j] += (float)w0[4 + j] * pk;
            a2[j] += (float)w1[j]     * pk;
            a3[j] += (float)w1[4 + j] * pk;
        }
    }
    float* dst = part + ((size_t)chunk * 32 + bh) * 4160 + (size_t)f * 65 + eg * 16;
    #pragma unroll
    for (int j = 0; j < 4; j++) { dst[j] = a0[j]; dst[4+j] = a1[j]; dst[8+j] = a2[j]; dst[12+j] = a3[j]; }
    if (eg == 0) dst[64] = psum;   // pksum slot
}

__global__ void kv_reduce(const float* __restrict__ part, float* __restrict__ kvfin) {
    int i = blockIdx.x * 256 + threadIdx.x;
    if (i >= 32 * 4160) return;
    float s = 0.f;
    #pragma unroll 8
    for (int c = 0; c < 64; c++) s += part[(size_t)c * (32 * 4160) + i];
    kvfin[i] = s;
}

// ---------------- num / den / divide -> attn (bf16), MFMA with den column ----
__global__ __launch_bounds__(256) void num_attn(const __bf16* __restrict__ qkvb,
                                                const float* __restrict__ kvfin,
                                                __bf16* __restrict__ attn) {
    __shared__ __bf16 kvb[64][86];
    __shared__ __bf16 cs[128][72];
    int bh = blockIdx.x, chunk = blockIdx.y;   // 32 x 32
    int b = bh >> 3, hh = bh & 7;
    const float* src = kvfin + (size_t)bh * 4160;
    int t = threadIdx.x;
    for (int i = t; i < 4096; i += 256) {
        int f = i >> 6, e = i & 63;
        kvb[f][e] = (__bf16)src[f * 65 + e];
    }
    if (t < 64) {
        kvb[t][64] = (__bf16)src[t * 65 + 64];     // ps column
        #pragma unroll
        for (int e = 65; e < 80; e++) kvb[t][e] = (__bf16)0.f;
    }
    const int lane = t & 63, w = t >> 6;
    const int fr = lane & 15, fc = lane >> 4;
    size_t rowbase = (size_t)b * SEQ + (size_t)chunk * 128 + w * 32;
    bf16x8 a[2][2];
    #pragma unroll
    for (int rt = 0; rt < 2; rt++)
        #pragma unroll
        for (int ks = 0; ks < 2; ks++)
            a[rt][ks] = *(const bf16x8*)(qkvb + (rowbase + rt * 16 + fr) * 1536 + hh * 64 + ks * 32 + fc * 8);
    __syncthreads();   // kvb visible
    bf16x8 bfrag[5][2];
    #pragma unroll
    for (int n = 0; n < 5; n++)
        #pragma unroll
        for (int ks = 0; ks < 2; ks++) {
            bf16x8 bv;
            #pragma unroll
            for (int j = 0; j < 8; j++) bv[j] = kvb[ks * 32 + fc * 8 + j][n * 16 + fr];
            bfrag[n][ks] = bv;
        }
    f32x4 acc[2][5];
    #pragma unroll
    for (int rt = 0; rt < 2; rt++)
        #pragma unroll
        for (int n = 0; n < 5; n++)
            acc[rt][n] = (f32x4){0.f, 0.f, 0.f, 0.f};
    #pragma unroll
    for (int ks = 0; ks < 2; ks++)
        #pragma unroll
        for (int rt = 0; rt < 2; rt++)
            #pragma unroll
            for (int n = 0; n < 5; n++)
                acc[rt][n] = __builtin_amdgcn_mfma_f32_16x16x32_bf16(a[rt][ks], bfrag[n][ks], acc[rt][n], 0, 0, 0);
    const int cr = (lane >> 4) * 4, cc = lane & 15;
    #pragma unroll
    for (int rt = 0; rt < 2; rt++) {
        float rdv[4];
        #pragma unroll
        for (int r2 = 0; r2 < 4; r2++)
            rdv[r2] = 1.f / __shfl(acc[rt][4][r2], lane & 48);   // den from cc==0 lane
        #pragma unroll
        for (int r2 = 0; r2 < 4; r2++) {
            int lr = w * 32 + rt * 16 + cr + r2;
            #pragma unroll
            for (int n = 0; n < 4; n++)
                cs[lr][n * 16 + cc] = (__bf16)(acc[rt][n][r2] * rdv[r2]);
        }
    }
    __syncthreads();
    size_t base = (size_t)b * SEQ + (size_t)chunk * 128;
    for (int i = t; i < 128 * 8; i += 256) {
        int row = i >> 3, c8 = i & 7;
        bf16x8 v = *(const bf16x8*)(&cs[row][c8 * 8]);
        *(bf16x8*)(attn + (base + row) * 512 + hh * 64 + c8 * 8) = v;
    }
}

extern "C" void kernel_launch(void* const* d_in, const int* in_sizes, int n_in,
                              void* d_out, int out_size, void* d_ws, size_t ws_size,
                              hipStream_t stream) {
    const int*   tokens = (const int*)d_in[0];
    const float* embed  = (const float*)d_in[1];
    const float* Wq     = (const float*)d_in[2];
    const float* Wk     = (const float*)d_in[3];
    const float* Wv     = (const float*)d_in[4];
    const float* Wo     = (const float*)d_in[5];
    const float* ln1_s  = (const float*)d_in[6];
    const float* ln1_b  = (const float*)d_in[7];
    const float* W1     = (const float*)d_in[8];
    const float* b1     = (const float*)d_in[9];
    const float* W2     = (const float*)d_in[10];
    const float* b2     = (const float*)d_in[11];
    const float* ln2_s  = (const float*)d_in[12];
    const float* ln2_b  = (const float*)d_in[13];
    const float* lnf_s  = (const float*)d_in[14];
    const float* lnf_b  = (const float*)d_in[15];
    float* out = (float*)d_out;

    float* ws = (float*)d_ws;
    size_t off = 0;
    float* pos = ws;               off += 2097152;            // 4096*512 f32
    float* x   = ws + off;         off += 8388608;            // 16384*512 f32
    __bf16* h    = (__bf16*)(ws + off); off += 4194304;       // 16384*512 bf16
    __bf16* attn = (__bf16*)(ws + off); off += 4194304;       // 16384*512 bf16
    __bf16* qkvb = (__bf16*)(ws + off);                       // 16384*1536 bf16
    __bf16* hid  = (__bf16*)(ws + off); off += 16777216;      // 16384*2048 bf16 (union, serialized)
    float* kvpart = ws + off;      off += 64 * 32 * 4160;     // partials (64 chunks)
    float* kvfin  = ws + off;      off += 32 * 4160;
    __bf16* wbuf  = (__bf16*)(ws + off);                      // 6 * 3145728 bf16

    pos_kernel<<<4096, 256, 0, stream>>>(pos);
    transpose_bf16<<<dim3(16, 16, 6), dim3(32, 8), 0, stream>>>(Wq, wbuf,          512, 512,  262144, 3145728);
    transpose_bf16<<<dim3(16, 16, 6), dim3(32, 8), 0, stream>>>(Wk, wbuf + 262144, 512, 512,  262144, 3145728);
    transpose_bf16<<<dim3(16, 16, 6), dim3(32, 8), 0, stream>>>(Wv, wbuf + 524288, 512, 512,  262144, 3145728);
    transpose_bf16<<<dim3(16, 16, 6), dim3(32, 8), 0, stream>>>(Wo, wbuf + 786432, 512, 512,  262144, 3145728);
    transpose_bf16<<<dim3(64, 16, 6), dim3(32, 8), 0, stream>>>(W1, wbuf + 1048576, 512, 2048, 1048576, 3145728);
    transpose_bf16<<<dim3(16, 64, 6), dim3(32, 8), 0, stream>>>(W2, wbuf + 2097152, 2048, 512, 1048576, 3145728);
    embed_ln<<<4096, 256, 0, stream>>>(tokens, embed, pos, ln1_s, ln1_b, x, h);

    for (int l = 0; l < 6; l++) {
        const __bf16* wl = wbuf + (size_t)l * 3145728;
        gemm_bt<1, 512><<<768, 512, 0, stream>>>(h, wl, qkvb, nullptr, 1536, 12);
        kv_partial<<<dim3(32, 64), 256, 0, stream>>>(qkvb, kvpart);
        kv_reduce<<<520, 256, 0, stream>>>(kvpart, kvfin);
        num_attn<<<dim3(32, 32), 256, 0, stream>>>(qkvb, kvfin, attn);
        // Wo + residual + LN2 fused
        gemm_ln<0, 512, 0><<<256, 1024, 0, stream>>>(attn, wl + 786432, nullptr, x,
                                                     ln2_s + l * 512, ln2_b + l * 512, h, nullptr);
        gemm_bt<3, 512><<<1024, 512, 0, stream>>>(h, wl + 1048576, hid, b1 + (size_t)l * 2048, 2048, 16);
        // MLP2 + bias + residual + LN1(next) / LNf fused
        if (l < 5) {
            gemm_ln<1, 2048, 0><<<256, 1024, 0, stream>>>(hid, wl + 2097152, b2 + (size_t)l * 512, x,
                                                          ln1_s + (l + 1) * 512, ln1_b + (l + 1) * 512, h, nullptr);
        } else {
            gemm_ln<1, 2048, 1><<<256, 1024, 0, stream>>>(hid, wl + 2097152, b2 + (size_t)l * 512, x,
                                                          lnf_s, lnf_b, nullptr, out);
        }
    }
}